// Round 1
// baseline (163.644 us; speedup 1.0000x reference)
//
#include <hip/hip_runtime.h>
#include <float.h>

#define N_BINS 20
#define C 128

// ---------------------------------------------------------------------------
// Kernel 1: zero the 40-float accumulator region of the workspace.
// (Harness poisons d_ws once and never re-poisons between timed replays, so
//  we must re-zero on every call.)
// ---------------------------------------------------------------------------
__global__ void ece_init(float* __restrict__ ws) {
    int t = threadIdx.x;
    if (t < 2 * N_BINS) ws[t] = 0.0f;
}

// ---------------------------------------------------------------------------
// Kernel 2: per-row max/argmax + binned accumulation.
// Layout: block = 256 threads = 4 waves. Each wave handles 2 rows/iter:
//   lane 0..31  -> row r   (float4 at offset (lane&31)*16 B)
//   lane 32..63 -> row r+1
// One wave's 64 float4 loads cover exactly 1024 B = two contiguous rows
// -> perfectly coalesced global_load_dwordx4.
// ---------------------------------------------------------------------------
__global__ __launch_bounds__(256) void ece_main(const float* __restrict__ outs,
                                                const int* __restrict__ labels,
                                                float* __restrict__ ws,
                                                int n_rows, int total_waves) {
    __shared__ float s_conf[N_BINS];
    __shared__ float s_acc[N_BINS];

    const int tid = threadIdx.x;
    if (tid < N_BINS) {
        s_conf[tid] = 0.0f;
        s_acc[tid]  = 0.0f;
    }
    __syncthreads();

    const int lane  = tid & 63;
    const int wave  = tid >> 6;
    const int l32   = lane & 31;          // position within the 32-lane half
    const int half  = lane >> 5;          // 0 -> row r, 1 -> row r+1
    const long long gwave  = (long long)blockIdx.x * 4 + wave;
    const long long stride = (long long)total_waves * 2;

    for (long long r0 = gwave * 2; r0 < n_rows; r0 += stride) {
        const long long row = r0 + half;

        float bestVal = -FLT_MAX;
        int   bestIdx = 0x7fffffff;

        if (row < n_rows) {
            const float4* p =
                reinterpret_cast<const float4*>(outs + row * C) + l32;
            const float4 v = *p;
            const int base = l32 * 4;
            bestVal = v.x; bestIdx = base;
            if (v.y > bestVal) { bestVal = v.y; bestIdx = base + 1; }
            if (v.z > bestVal) { bestVal = v.z; bestIdx = base + 2; }
            if (v.w > bestVal) { bestVal = v.w; bestIdx = base + 3; }
        }

        // Butterfly reduce within each 32-lane half (xor masks 1..16 never
        // cross bit 5, so rows don't mix). Lowest-index tiebreak to match
        // jnp.argmax first-occurrence semantics.
        #pragma unroll
        for (int m = 1; m <= 16; m <<= 1) {
            const float ov = __shfl_xor(bestVal, m);
            const int   oi = __shfl_xor(bestIdx, m);
            if (ov > bestVal || (ov == bestVal && oi < bestIdx)) {
                bestVal = ov;
                bestIdx = oi;
            }
        }

        if (l32 == 0 && row < n_rows) {
            // bin = clip(ceil(conf*20) - 1, 0, 19): identical f32 arithmetic
            // to the reference's jnp.ceil(conf * N_BINS) path.
            int bin = (int)ceilf(bestVal * (float)N_BINS) - 1;
            bin = min(max(bin, 0), N_BINS - 1);
            const float accv = (bestIdx == labels[row]) ? 1.0f : 0.0f;
            atomicAdd(&s_conf[bin], bestVal);
            atomicAdd(&s_acc[bin], accv);
        }
    }

    __syncthreads();
    if (tid < N_BINS) {
        atomicAdd(&ws[tid], s_conf[tid]);
    } else if (tid < 2 * N_BINS) {
        atomicAdd(&ws[tid], s_acc[tid - N_BINS]);
    }
}

// ---------------------------------------------------------------------------
// Kernel 3: ece = sum_b |sum_conf_b - sum_acc_b| / N
// ---------------------------------------------------------------------------
__global__ void ece_final(const float* __restrict__ ws,
                          float* __restrict__ out, float inv_n) {
    const int t = threadIdx.x;   // 64 threads
    float d = (t < N_BINS) ? fabsf(ws[t] - ws[t + N_BINS]) : 0.0f;
    #pragma unroll
    for (int m = 1; m <= 32; m <<= 1) d += __shfl_xor(d, m);
    if (t == 0) out[0] = d * inv_n;
}

extern "C" void kernel_launch(void* const* d_in, const int* in_sizes, int n_in,
                              void* d_out, int out_size, void* d_ws, size_t ws_size,
                              hipStream_t stream) {
    const float* outs   = (const float*)d_in[0];
    const int*   labels = (const int*)d_in[1];
    float*       out    = (float*)d_out;
    float*       ws     = (float*)d_ws;

    const int n_rows = in_sizes[1];       // labels count == N
    const int blocks = 2048;              // grid-stride; ~8 waves/CU-slot worth
    const int total_waves = blocks * 4;

    hipLaunchKernelGGL(ece_init, dim3(1), dim3(64), 0, stream, ws);
    hipLaunchKernelGGL(ece_main, dim3(blocks), dim3(256), 0, stream,
                       outs, labels, ws, n_rows, total_waves);
    hipLaunchKernelGGL(ece_final, dim3(1), dim3(64), 0, stream,
                       ws, out, 1.0f / (float)n_rows);
}

// Round 2
// 120.725 us; speedup vs baseline: 1.3555x; 1.3555x over previous
//
#include <hip/hip_runtime.h>
#include <float.h>

#define N_BINS 20
#define C 128

// ---------------------------------------------------------------------------
// Kernel 1: zero the 40-float accumulator region of the workspace.
// (Harness poisons d_ws once and never re-poisons between timed replays.)
// ---------------------------------------------------------------------------
__global__ void ece_init(float* __restrict__ ws) {
    int t = threadIdx.x;
    if (t < 2 * N_BINS) ws[t] = 0.0f;
}

// ---------------------------------------------------------------------------
// Kernel 2: per-row max/argmax + binned accumulation.
//
// Layout: 8 lanes per row; each lane loads 4x float4 (64 B) of its row:
//   lane l -> row (base + (l>>3)), float4 #( (l&7) + 8*j ), j=0..3
// Per load instruction the wave touches 8 rows x 128 B contiguous chunks
// (128-B aligned, fully consumed) -> coalesced. Cross-lane reduce is only
// 3 xor-shuffle steps within 8-lane groups (vs 5 over 32 lanes before):
// LDS-pipe ops drop ~7x per byte, and each lane has 4 independent loads
// in flight.
// ---------------------------------------------------------------------------
__global__ __launch_bounds__(256) void ece_main(const float* __restrict__ outs,
                                                const int* __restrict__ labels,
                                                float* __restrict__ ws,
                                                int n_rows, int n_waves) {
    __shared__ float s_conf[N_BINS];
    __shared__ float s_acc[N_BINS];

    const int tid = threadIdx.x;
    if (tid < N_BINS) {
        s_conf[tid] = 0.0f;
        s_acc[tid]  = 0.0f;
    }
    __syncthreads();

    const int lane = tid & 63;
    const int sub  = lane & 7;    // chunk index within the row
    const int rsub = lane >> 3;   // which of the wave's 8 rows
    const int gwave = blockIdx.x * 4 + (tid >> 6);

    const float4* __restrict__ outs4 = reinterpret_cast<const float4*>(outs);

    for (int rowBase = gwave * 8; rowBase < n_rows; rowBase += n_waves * 8) {
        const int row = rowBase + rsub;
        const bool live = (row < n_rows);

        // Prefetch label early (leader lanes only); latency hides under
        // the loads + reduce below.
        int lab = -1;
        if (sub == 0 && live) lab = labels[row];

        float bestVal = -FLT_MAX;
        int   bestIdx = 0x7fffffff;

        if (live) {
            const float4* p = outs4 + row * (C / 4) + sub;
            float4 v[4];
            #pragma unroll
            for (int j = 0; j < 4; ++j) v[j] = p[j * 8];

            // element index of v[j].c within the row = sub*4 + j*32 + c;
            // scan in increasing-index order with strict '>' so the first
            // occurrence wins (matches jnp.argmax).
            const int base = sub * 4;
            #pragma unroll
            for (int j = 0; j < 4; ++j) {
                const int b = base + j * 32;
                if (v[j].x > bestVal) { bestVal = v[j].x; bestIdx = b;     }
                if (v[j].y > bestVal) { bestVal = v[j].y; bestIdx = b + 1; }
                if (v[j].z > bestVal) { bestVal = v[j].z; bestIdx = b + 2; }
                if (v[j].w > bestVal) { bestVal = v[j].w; bestIdx = b + 3; }
            }
        }

        // 3-step butterfly within each 8-lane group (xor masks 1,2,4 never
        // leave the group). Lowest-index tiebreak.
        #pragma unroll
        for (int m = 1; m <= 4; m <<= 1) {
            const float ov = __shfl_xor(bestVal, m);
            const int   oi = __shfl_xor(bestIdx, m);
            if (ov > bestVal || (ov == bestVal && oi < bestIdx)) {
                bestVal = ov;
                bestIdx = oi;
            }
        }

        if (sub == 0 && live) {
            // bin = clip(ceil(conf*20) - 1, 0, 19): same f32 arithmetic as
            // the reference.
            int bin = (int)ceilf(bestVal * (float)N_BINS) - 1;
            bin = min(max(bin, 0), N_BINS - 1);
            atomicAdd(&s_conf[bin], bestVal);
            atomicAdd(&s_acc[bin], (bestIdx == lab) ? 1.0f : 0.0f);
        }
    }

    __syncthreads();
    if (tid < N_BINS) {
        atomicAdd(&ws[tid], s_conf[tid]);
    } else if (tid < 2 * N_BINS) {
        atomicAdd(&ws[tid], s_acc[tid - N_BINS]);
    }
}

// ---------------------------------------------------------------------------
// Kernel 3: ece = sum_b |sum_conf_b - sum_acc_b| / N
// ---------------------------------------------------------------------------
__global__ void ece_final(const float* __restrict__ ws,
                          float* __restrict__ out, float inv_n) {
    const int t = threadIdx.x;   // 64 threads
    float d = (t < N_BINS) ? fabsf(ws[t] - ws[t + N_BINS]) : 0.0f;
    #pragma unroll
    for (int m = 1; m <= 32; m <<= 1) d += __shfl_xor(d, m);
    if (t == 0) out[0] = d * inv_n;
}

extern "C" void kernel_launch(void* const* d_in, const int* in_sizes, int n_in,
                              void* d_out, int out_size, void* d_ws, size_t ws_size,
                              hipStream_t stream) {
    const float* outs   = (const float*)d_in[0];
    const int*   labels = (const int*)d_in[1];
    float*       out    = (float*)d_out;
    float*       ws     = (float*)d_ws;

    const int n_rows  = in_sizes[1];   // labels count == N
    const int blocks  = 2048;          // 8 blocks/CU -> 32 waves/CU
    const int n_waves = blocks * 4;

    hipLaunchKernelGGL(ece_init, dim3(1), dim3(64), 0, stream, ws);
    hipLaunchKernelGGL(ece_main, dim3(blocks), dim3(256), 0, stream,
                       outs, labels, ws, n_rows, n_waves);
    hipLaunchKernelGGL(ece_final, dim3(1), dim3(64), 0, stream,
                       ws, out, 1.0f / (float)n_rows);
}